// Round 6
// baseline (737.521 us; speedup 1.0000x reference)
//
#include <hip/hip_runtime.h>
#include <math.h>

#define NTOK 16384
#define HDIM 2048
#define NEXP 64
#define TOPK 6
#define TB   64          // tokens per block = lanes per wave
#define CH   64          // h per chunk
#define NCH  (HDIM / CH) // 32 chunks
#define ER   16          // experts per wave (4 waves cover 64)

// xs[buf][quad][token]: transposed x chunk; compute reads are 64-lane
// contiguous 1KB (zero-conflict, R5-proven). lg overlays after final barrier.
union SMem {
    float4 xs[2][16][TB];        // 32 KB
    float  lg[TB][NEXP + 1];     // 16.6 KB overlay
};

#define FMA4(A, X, W)                      \
    A.x = fmaf(X.x, W.x, A.x);             \
    A.y = fmaf(X.y, W.y, A.y);             \
    A.z = fmaf(X.z, W.z, A.z);             \
    A.w = fmaf(X.w, W.w, A.w);

__global__ __launch_bounds__(256) void moe_gate_kernel(
        const float* __restrict__ x,
        const float* __restrict__ w,
        float* __restrict__ out)
{
    __shared__ SMem sm;

    const int tid   = threadIdx.x;
    const int lane  = tid & 63;                                 // = token
    const int wv    = __builtin_amdgcn_readfirstlane(tid >> 6); // e-group
    const int ebase = wv * ER;
    const int tbase = blockIdx.x * TB;

    // staging roles: thread t stages token (st+16k), quad sq  (coalesced 16B runs)
    const int sq = tid & 15;
    const int st = tid >> 4;

    // acc[e]: float4 j-partials (j = h%4, ascending h over ALL chunks) for
    // (token = lane, expert = ebase+e). Bit-identical accumulation to R1.
    float4 acc[ER];
    #pragma unroll
    for (int e = 0; e < ER; ++e) acc[e] = make_float4(0.f, 0.f, 0.f, 0.f);

    // ---- prologue: stage chunk 0 ----
    float4 pf[4];
    #pragma unroll
    for (int k = 0; k < 4; ++k)
        pf[k] = *(const float4*)&x[(size_t)(tbase + st + 16 * k) * HDIM + 4 * sq];
    #pragma unroll
    for (int k = 0; k < 4; ++k)
        sm.xs[0][sq][st + 16 * k] = pf[k];
    __syncthreads();

    for (int c = 0; c < NCH; ++c) {
        const int cur = c & 1;

        // prefetch next chunk into registers (vmcnt path, hides under fma)
        if (c + 1 < NCH) {
            #pragma unroll
            for (int k = 0; k < 4; ++k)
                pf[k] = *(const float4*)&x[(size_t)(tbase + st + 16 * k) * HDIM
                                           + (c + 1) * CH + 4 * sq];
        }

        // pull own token's chunk row: 16 contiguous ds_read_b128, then LDS idle
        float4 xq[16];
        #pragma unroll
        for (int s = 0; s < 16; ++s)
            xq[s] = sm.xs[cur][s][lane];

        // e-outer FMA: per expert 16 consecutive uniform w-loads (scalarizes,
        // lgkm waits here see only s_loads) + 64 v_fma (4 independent j-chains)
        const float* wc = w + (size_t)ebase * HDIM + c * CH;
        #pragma unroll
        for (int e = 0; e < ER; ++e) {
            const float* we = wc + (size_t)e * HDIM;
            #pragma unroll
            for (int s = 0; s < 16; ++s) {
                const float4 wq = *(const float4*)(we + 4 * s);
                FMA4(acc[e], xq[s], wq)
            }
        }

        // stage next chunk into the other buffer (its readers finished at the
        // barrier that ended iteration c-1); one barrier per chunk
        if (c + 1 < NCH) {
            #pragma unroll
            for (int k = 0; k < 4; ++k)
                sm.xs[cur ^ 1][sq][st + 16 * k] = pf[k];
        }
        __syncthreads();
    }

    // ---- logits: np SSE combine (J0+J2)+(J1+J3), write to overlay ----
    #pragma unroll
    for (int e = 0; e < ER; ++e)
        sm.lg[lane][ebase + e] = (acc[e].x + acc[e].z) + (acc[e].y + acc[e].w);
    __syncthreads();

    // ---- per-token top-6 + softmax + renorm (identical numerics to R1) ----
    if (tid < TB) {
        float val[TOPK];
        int   idx[TOPK];
        #pragma unroll
        for (int k = 0; k < TOPK; ++k) { val[k] = -3.0e38f; idx[k] = 0; }

        for (int e = 0; e < NEXP; ++e) {
            float cv = sm.lg[tid][e];
            int   ci = e;
            #pragma unroll
            for (int k = 0; k < TOPK; ++k) {
                if (cv > val[k]) {                 // strict >: lowest index wins ties
                    const float tv = val[k]; const int ti = idx[k];
                    val[k] = cv; idx[k] = ci;
                    cv = tv; ci = ti;
                }
            }
        }

        const float m = val[0];
        float ex[TOPK];
        float s = 0.f;
        #pragma unroll
        for (int k = 0; k < TOPK; ++k) { ex[k] = expf(val[k] - m); s += ex[k]; }
        float p[TOPK];
        float d = 0.f;
        #pragma unroll
        for (int k = 0; k < TOPK; ++k) { p[k] = ex[k] / s; d += p[k]; }
        d += 1e-20f;

        const int tg = tbase + tid;
        float* oi = out;                           // idx chunk   [NTOK*TOPK]
        float* ow = out + (size_t)NTOK * TOPK;     // weight chunk
        #pragma unroll
        for (int k = 0; k < TOPK; ++k) {
            oi[tg * TOPK + k] = (float)idx[k];
            ow[tg * TOPK + k] = p[k] / d;
        }
    }
}

extern "C" void kernel_launch(void* const* d_in, const int* in_sizes, int n_in,
                              void* d_out, int out_size, void* d_ws, size_t ws_size,
                              hipStream_t stream) {
    const float* x = (const float*)d_in[0];
    const float* w = (const float*)d_in[1];
    float* out = (float*)d_out;
    dim3 grid(NTOK / TB);   // 256 blocks = 1 per CU
    dim3 block(256);        // 4 waves = 4 expert groups; lane = token
    hipLaunchKernelGGL(moe_gate_kernel, grid, block, 0, stream, x, w, out);
}